// Round 5
// baseline (126.832 us; speedup 1.0000x reference)
//
#include <hip/hip_runtime.h>
#include <math.h>

#define NN 1024      // N
#define DIN 512      // D_IN
#define DD 128       // D

// ws layout (floats): x[1024*128], z[1024*128], u[256]
static constexpr long X_OFF = 0;
static constexpr long Z_OFF = X_OFF + (long)NN * DD;
static constexpr long U_OFF = Z_OFF + (long)NN * DD;

// ---------------------------------------------------------------------------
// K1: x = inputs @ W direct (no split-K). grid (32 row-blocks, 4 col-blocks),
// 512 threads; thread -> cols by*32+tx, rows ty and ty+16. Also: zero z
// (atomic target of K2) and compute u = W2 @ w3[:128] on blocks 0..7.
__global__ __launch_bounds__(512) void k1_x_zeroz_u(
    const float* __restrict__ inputs, const float* __restrict__ W,
    const float* __restrict__ W2, const float* __restrict__ w3,
    float* __restrict__ x, float* __restrict__ z, float* __restrict__ u) {
  const int t = threadIdx.x;
  const int bx = blockIdx.x;   // 0..31
  const int by = blockIdx.y;   // 0..3
  const int blk = bx * 4 + by; // 0..127

  // zero z: 1024 floats per block (256 float4)
  if (t < 256) {
    float4 zz; zz.x = 0.f; zz.y = 0.f; zz.z = 0.f; zz.w = 0.f;
    ((float4*)z)[(long)blk * 256 + t] = zz;
  }

  const int tx = t & 31;
  const int ty = t >> 5;       // 0..15
  const int c  = by * 32 + tx;
  const int r0 = bx * 32 + ty;
  const float* A0 = inputs + (long)r0 * DIN;
  const float* A1 = inputs + (long)(r0 + 16) * DIN;
  float acc0 = 0.f, acc1 = 0.f;
#pragma unroll 4
  for (int k = 0; k < DIN; k += 4) {
    const float4 a0 = *(const float4*)&A0[k];
    const float4 a1 = *(const float4*)&A1[k];
    const float b0 = W[(long)k * DD + c];
    const float b1 = W[(long)(k + 1) * DD + c];
    const float b2 = W[(long)(k + 2) * DD + c];
    const float b3 = W[(long)(k + 3) * DD + c];
    acc0 += a0.x * b0 + a0.y * b1 + a0.z * b2 + a0.w * b3;
    acc1 += a1.x * b0 + a1.y * b1 + a1.z * b2 + a1.w * b3;
  }
  x[(long)r0 * DD + c] = acc0;
  x[(long)(r0 + 16) * DD + c] = acc1;

  // u: blocks 0..7 (flat), 32 rows of W2 each, 8 lanes per row
  if (blk < 8 && t < 256) {
    const int row = blk * 32 + (t >> 3);
    const int l8 = t & 7;
    float s = 0.f;
#pragma unroll
    for (int i = 0; i < 16; ++i) {
      const int l = l8 + 8 * i;
      s += W2[(long)row * DD + l] * w3[l];
    }
#pragma unroll
    for (int off = 4; off > 0; off >>= 1) s += __shfl_down(s, off, 8);
    if (l8 == 0) u[row] = s;
  }
}

// ---------------------------------------------------------------------------
// K2: z += adj @ x, split-K 8 via global fp32 atomics (z pre-zeroed by K1).
// grid (32 row-blocks, 8 k-splits), 256 threads, Kc=128. Thread (tx,ty):
// rows ty+8*mr, cols tx+32*mc, 16 independent accumulators.
__global__ __launch_bounds__(256) void k2_z_atomic(
    const float* __restrict__ adj, const float* __restrict__ x,
    float* __restrict__ z) {
  const int t = threadIdx.x;
  const int tx = t & 31;
  const int ty = t >> 5;
  const int row0 = blockIdx.x * 32;
  const int k0 = blockIdx.y * 128;

  float acc[4][4] = {};

  for (int k = k0; k < k0 + 128; k += 4) {
    float bv[4][4];
#pragma unroll
    for (int kk = 0; kk < 4; ++kk) {
      const float* Brow = &x[(long)(k + kk) * DD + tx];
#pragma unroll
      for (int mc = 0; mc < 4; ++mc) bv[kk][mc] = Brow[32 * mc];
    }
#pragma unroll
    for (int mr = 0; mr < 4; ++mr) {
      const int r = row0 + ty + 8 * mr;
      const float4 av = *(const float4*)&adj[(long)r * NN + k];
      const float ar[4] = {av.x, av.y, av.z, av.w};
#pragma unroll
      for (int kk = 0; kk < 4; ++kk)
#pragma unroll
        for (int mc = 0; mc < 4; ++mc) acc[mr][mc] += ar[kk] * bv[kk][mc];
    }
  }

#pragma unroll
  for (int mr = 0; mr < 4; ++mr) {
    const int r = row0 + ty + 8 * mr;
#pragma unroll
    for (int mc = 0; mc < 4; ++mc)
      atomicAdd(&z[(long)r * DD + tx + 32 * mc], acc[mr][mc]);
  }
}

// ---------------------------------------------------------------------------
// K3: out[i,j] = sigmoid(a[i] + b[j] + z_i . (z_j * w3[128:])) with a,b
// computed inline during staging. 64x64 tile, 256 threads, 4x4 per thread.
// j-side (scaled) staged in LDS (32 KB, XOR-swizzled -> conflict-free b128);
// i-side read from global z (64-row working set = 32 KB = L1-resident).
__global__ __launch_bounds__(256) void k3_decode(
    const float* __restrict__ z, const float* __restrict__ w3,
    const float* __restrict__ u, float* __restrict__ out) {
  __shared__ float zwl[64 * DD];   // z_j * w3[128:], swizzled
  __shared__ float a_loc[64];      // relu(z_i).u[:128]
  __shared__ float b_loc[64];      // relu(z_j).u[128:]
  const int t = threadIdx.x;
  const int i0 = blockIdx.y * 64;
  const int j0 = blockIdx.x * 64;

  // Staging: q-group (32 lanes x float4) covers one full 128-col row.
#pragma unroll
  for (int s = 0; s < 8; ++s) {
    const int q = s * 256 + t;      // 0..2047
    const int r = q >> 5;           // 0..63, one full row per 32-lane group
    const int k4 = (q & 31) << 2;   // 0..124
    const float4 u0 = *(const float4*)&u[k4];
    const float4 u1 = *(const float4*)&u[DD + k4];
    const float4 v = *(const float4*)&z[(long)(i0 + r) * DD + k4];
    float pa = fmaxf(v.x, 0.f) * u0.x + fmaxf(v.y, 0.f) * u0.y +
               fmaxf(v.z, 0.f) * u0.z + fmaxf(v.w, 0.f) * u0.w;
    float4 w = *(const float4*)&z[(long)(j0 + r) * DD + k4];
    float pb = fmaxf(w.x, 0.f) * u1.x + fmaxf(w.y, 0.f) * u1.y +
               fmaxf(w.z, 0.f) * u1.z + fmaxf(w.w, 0.f) * u1.w;
    const float4 cc = *(const float4*)&w3[DD + k4];
    w.x *= cc.x; w.y *= cc.y; w.z *= cc.z; w.w *= cc.w;
    *(float4*)&zwl[r * DD + (k4 ^ ((r & 7) << 2))] = w;
#pragma unroll
    for (int off = 16; off > 0; off >>= 1) {
      pa += __shfl_down(pa, off, 32);
      pb += __shfl_down(pb, off, 32);
    }
    if ((t & 31) == 0) { a_loc[r] = pa; b_loc[r] = pb; }
  }
  __syncthreads();

  const int tx = t & 15;
  const int ty = t >> 4;
  float acc[4][4] = {};
  for (int k4 = 0; k4 < DD; k4 += 4) {
    float4 ar[4], bc[4];
#pragma unroll
    for (int m = 0; m < 4; ++m)  // i-side from global (L1-resident rows)
      ar[m] = *(const float4*)&z[(long)(i0 + ty + 16 * m) * DD + k4];
#pragma unroll
    for (int m = 0; m < 4; ++m) {
      const int C = tx + 16 * m;
      bc[m] = *(const float4*)&zwl[C * DD + (k4 ^ ((C & 7) << 2))];
    }
#pragma unroll
    for (int mr = 0; mr < 4; ++mr)
#pragma unroll
      for (int mc = 0; mc < 4; ++mc)
        acc[mr][mc] += ar[mr].x * bc[mc].x + ar[mr].y * bc[mc].y +
                       ar[mr].z * bc[mc].z + ar[mr].w * bc[mc].w;
  }

#pragma unroll
  for (int mr = 0; mr < 4; ++mr) {
    const int i = i0 + ty + 16 * mr;
    const float ai = a_loc[ty + 16 * mr];
#pragma unroll
    for (int mc = 0; mc < 4; ++mc) {
      const int j = j0 + tx + 16 * mc;
      const float s = ai + b_loc[tx + 16 * mc] + acc[mr][mc];
      out[(long)i * NN + j] = 1.0f / (1.0f + __expf(-s));
    }
  }
}

// ---------------------------------------------------------------------------
extern "C" void kernel_launch(void* const* d_in, const int* in_sizes, int n_in,
                              void* d_out, int out_size, void* d_ws, size_t ws_size,
                              hipStream_t stream) {
  (void)in_sizes; (void)n_in; (void)out_size; (void)ws_size;
  const float* inputs = (const float*)d_in[0];   // (1024, 512)
  const float* adj    = (const float*)d_in[1];   // (1024, 1024)
  const float* weight = (const float*)d_in[2];   // (512, 128)
  const float* W2     = (const float*)d_in[3];   // (256, 128)
  const float* w3     = (const float*)d_in[4];   // (256,)
  float* out = (float*)d_out;

  float* ws = (float*)d_ws;
  float* x = ws + X_OFF;
  float* z = ws + Z_OFF;
  float* u = ws + U_OFF;

  // K1: x = inputs@W ; zero z ; u = W2@w3[:128]
  k1_x_zeroz_u<<<dim3(32, 4), 512, 0, stream>>>(inputs, weight, W2, w3, x, z, u);
  // K2: z += adj@x (split-K 8, atomics)
  k2_z_atomic<<<dim3(32, 8), 256, 0, stream>>>(adj, x, z);
  // K3: decode with inline a,b
  k3_decode<<<dim3(16, 16), 256, 0, stream>>>(z, w3, u, out);
}

// Round 6
// 125.056 us; speedup vs baseline: 1.0142x; 1.0142x over previous
//
#include <hip/hip_runtime.h>
#include <math.h>

#define NN 1024      // N
#define DIN 512      // D_IN
#define DD 128       // D

static constexpr long S = (long)NN * DD;   // 131072 floats
// ws layout (floats)
static constexpr long ZP_OFF = 0;          // 8 z-partials
static constexpr long X_OFF  = ZP_OFF + 8 * S;
static constexpr long Z_OFF  = X_OFF + S;
static constexpr long U_OFF  = Z_OFF + S;
static constexpr long A_OFF  = U_OFF + 256;
static constexpr long B_OFF  = A_OFF + NN;

// ---------------------------------------------------------------------------
// K1: x = inputs @ W direct. grid (32 row-blocks, 4 col-blocks), 512 thr.
// Thread -> col by*32+tx, rows bx*32+ty and +16 (2-way ILP, K=512).
// W column stream: 32 consecutive cols per block, L1-resident (64 KB).
// Blocks 0..7 (flat) also compute u = W2 @ w3[:128].
__global__ __launch_bounds__(512) void k1_x_u(
    const float* __restrict__ inputs, const float* __restrict__ W,
    const float* __restrict__ W2, const float* __restrict__ w3,
    float* __restrict__ x, float* __restrict__ u) {
  const int t = threadIdx.x;
  const int bx = blockIdx.x;   // 0..31
  const int by = blockIdx.y;   // 0..3
  const int tx = t & 31;
  const int ty = t >> 5;       // 0..15
  const int c  = by * 32 + tx;
  const int r0 = bx * 32 + ty;
  const float* A0 = inputs + (long)r0 * DIN;
  const float* A1 = inputs + (long)(r0 + 16) * DIN;
  float acc0 = 0.f, acc1 = 0.f;
#pragma unroll 4
  for (int k = 0; k < DIN; k += 4) {
    const float4 a0 = *(const float4*)&A0[k];
    const float4 a1 = *(const float4*)&A1[k];
    const float b0 = W[(long)k * DD + c];
    const float b1 = W[(long)(k + 1) * DD + c];
    const float b2 = W[(long)(k + 2) * DD + c];
    const float b3 = W[(long)(k + 3) * DD + c];
    acc0 += a0.x * b0 + a0.y * b1 + a0.z * b2 + a0.w * b3;
    acc1 += a1.x * b0 + a1.y * b1 + a1.z * b2 + a1.w * b3;
  }
  x[(long)r0 * DD + c] = acc0;
  x[(long)(r0 + 16) * DD + c] = acc1;

  const int blk = bx * 4 + by;
  if (blk < 8 && t < 256) {
    const int row = blk * 32 + (t >> 3);
    const int l8 = t & 7;
    float s = 0.f;
#pragma unroll
    for (int i = 0; i < 16; ++i) {
      const int l = l8 + 8 * i;
      s += W2[(long)row * DD + l] * w3[l];
    }
#pragma unroll
    for (int off = 4; off > 0; off >>= 1) s += __shfl_down(s, off, 8);
    if (l8 == 0) u[row] = s;
  }
}

// ---------------------------------------------------------------------------
// K2: zp[split] = adj @ x partials, split-K 8. grid (32,8), 256 thr, Kc=128.
// Thread (tx,ty): rows ty+8*mr, cols tx+32*mc — 16 independent accumulators.
__global__ __launch_bounds__(256) void k2_zp(
    const float* __restrict__ adj, const float* __restrict__ x,
    float* __restrict__ zp) {
  const int t = threadIdx.x;
  const int tx = t & 31;
  const int ty = t >> 5;
  const int row0 = blockIdx.x * 32;
  const int k0 = blockIdx.y * 128;

  float acc[4][4] = {};

  for (int k = k0; k < k0 + 128; k += 4) {
    float bv[4][4];
#pragma unroll
    for (int kk = 0; kk < 4; ++kk) {
      const float* Brow = &x[(long)(k + kk) * DD + tx];
#pragma unroll
      for (int mc = 0; mc < 4; ++mc) bv[kk][mc] = Brow[32 * mc];
    }
#pragma unroll
    for (int mr = 0; mr < 4; ++mr) {
      const int r = row0 + ty + 8 * mr;
      const float4 av = *(const float4*)&adj[(long)r * NN + k];
      const float ar[4] = {av.x, av.y, av.z, av.w};
#pragma unroll
      for (int kk = 0; kk < 4; ++kk)
#pragma unroll
        for (int mc = 0; mc < 4; ++mc) acc[mr][mc] += ar[kk] * bv[kk][mc];
    }
  }

  float* Cs = zp + (long)blockIdx.y * S;
#pragma unroll
  for (int mr = 0; mr < 4; ++mr) {
    const int r = row0 + ty + 8 * mr;
#pragma unroll
    for (int mc = 0; mc < 4; ++mc)
      Cs[(long)r * DD + tx + 32 * mc] = acc[mr][mc];
  }
}

// ---------------------------------------------------------------------------
// K3: reduce 8 z-partials -> z ; fused a_i = relu(z_i).u[:128],
// b_i = relu(z_i).u[128:]. grid = 1024 rows, block = 128 (col per thread).
__global__ __launch_bounds__(128) void k3_finalize(
    const float* __restrict__ zp, float* __restrict__ z,
    const float* __restrict__ u, float* __restrict__ a, float* __restrict__ b) {
  __shared__ float red[2][2];
  const int i = blockIdx.x;
  const int c = threadIdx.x;  // 0..127
  float s = 0.f;
#pragma unroll
  for (int p = 0; p < 8; ++p) s += zp[p * S + (long)i * DD + c];
  z[(long)i * DD + c] = s;

  const float r = s > 0.f ? s : 0.f;
  float pa = r * u[c];
  float pb = r * u[DD + c];
#pragma unroll
  for (int off = 32; off > 0; off >>= 1) {
    pa += __shfl_down(pa, off);
    pb += __shfl_down(pb, off);
  }
  const int w = c >> 6;
  if ((c & 63) == 0) { red[w][0] = pa; red[w][1] = pb; }
  __syncthreads();
  if (c == 0) {
    a[i] = red[0][0] + red[1][0];
    b[i] = red[0][1] + red[1][1];
  }
}

// ---------------------------------------------------------------------------
// K4: out[i,j] = sigmoid(a[i] + b[j] + z_i . (z_j * w3[128:])).
// 64x64 tile, 256 threads, 4x4 per thread. j-side (scaled) in LDS
// (32 KB, XOR-swizzled -> conflict-free b128 column reads); i-side from
// global z (64-row working set = 32 KB = L1-resident; VMEM overlaps LDS).
__global__ __launch_bounds__(256) void k4_decode(
    const float* __restrict__ z, const float* __restrict__ w3,
    const float* __restrict__ a, const float* __restrict__ b,
    float* __restrict__ out) {
  __shared__ float zwl[64 * DD];
  const int t = threadIdx.x;
  const int i0 = blockIdx.y * 64;
  const int j0 = blockIdx.x * 64;

  // Stage j-side: 2048 float4s over 8 iters; 32-lane group = one full row.
#pragma unroll
  for (int s = 0; s < 8; ++s) {
    const int q = s * 256 + t;
    const int r = q >> 5;
    const int k4 = (q & 31) << 2;
    float4 w = *(const float4*)&z[(long)(j0 + r) * DD + k4];
    const float4 cc = *(const float4*)&w3[DD + k4];
    w.x *= cc.x; w.y *= cc.y; w.z *= cc.z; w.w *= cc.w;
    *(float4*)&zwl[r * DD + (k4 ^ ((r & 7) << 2))] = w;
  }
  __syncthreads();

  const int tx = t & 15;
  const int ty = t >> 4;
  float acc[4][4] = {};
  for (int k4 = 0; k4 < DD; k4 += 4) {
    float4 ar[4], bc[4];
#pragma unroll
    for (int m = 0; m < 4; ++m)  // i-side from global (L1-resident)
      ar[m] = *(const float4*)&z[(long)(i0 + ty + 16 * m) * DD + k4];
#pragma unroll
    for (int m = 0; m < 4; ++m) {
      const int C = tx + 16 * m;
      bc[m] = *(const float4*)&zwl[C * DD + (k4 ^ ((C & 7) << 2))];
    }
#pragma unroll
    for (int mr = 0; mr < 4; ++mr)
#pragma unroll
      for (int mc = 0; mc < 4; ++mc)
        acc[mr][mc] += ar[mr].x * bc[mc].x + ar[mr].y * bc[mc].y +
                       ar[mr].z * bc[mc].z + ar[mr].w * bc[mc].w;
  }

#pragma unroll
  for (int mr = 0; mr < 4; ++mr) {
    const int i = i0 + ty + 16 * mr;
    const float ai = a[i];
#pragma unroll
    for (int mc = 0; mc < 4; ++mc) {
      const int j = j0 + tx + 16 * mc;
      const float sc = ai + b[j] + acc[mr][mc];
      out[(long)i * NN + j] = 1.0f / (1.0f + __expf(-sc));
    }
  }
}

// ---------------------------------------------------------------------------
extern "C" void kernel_launch(void* const* d_in, const int* in_sizes, int n_in,
                              void* d_out, int out_size, void* d_ws, size_t ws_size,
                              hipStream_t stream) {
  (void)in_sizes; (void)n_in; (void)out_size; (void)ws_size;
  const float* inputs = (const float*)d_in[0];   // (1024, 512)
  const float* adj    = (const float*)d_in[1];   // (1024, 1024)
  const float* weight = (const float*)d_in[2];   // (512, 128)
  const float* W2     = (const float*)d_in[3];   // (256, 128)
  const float* w3     = (const float*)d_in[4];   // (256,)
  float* out = (float*)d_out;

  float* ws = (float*)d_ws;
  float* zp = ws + ZP_OFF;
  float* x  = ws + X_OFF;
  float* z  = ws + Z_OFF;
  float* u  = ws + U_OFF;
  float* a  = ws + A_OFF;
  float* b  = ws + B_OFF;

  // K1: x = inputs@W (direct) ; u = W2@w3[:128]
  k1_x_u<<<dim3(32, 4), 512, 0, stream>>>(inputs, weight, W2, w3, x, u);
  // K2: zp = adj@x partials (split-K 8)
  k2_zp<<<dim3(32, 8), 256, 0, stream>>>(adj, x, zp);
  // K3: z = sum(zp) ; a,b
  k3_finalize<<<1024, 128, 0, stream>>>(zp, z, u, a, b);
  // K4: decode
  k4_decode<<<dim3(16, 16), 256, 0, stream>>>(z, w3, a, b, out);
}

// Round 7
// 110.267 us; speedup vs baseline: 1.1502x; 1.1341x over previous
//
#include <hip/hip_runtime.h>
#include <math.h>

#define NN 1024      // N
#define DIN 512      // D_IN
#define DD 128       // D

static constexpr long S = (long)NN * DD;       // 131072 floats per matrix
// ws layout (floats)
static constexpr long XP_OFF = 0;              // 16 x-partials
static constexpr long ZP_OFF = XP_OFF + 16 * S;
static constexpr long X_OFF  = ZP_OFF + 32 * S;  // 32 z-partials
static constexpr long Z_OFF  = X_OFF + S;
static constexpr long U_OFF  = Z_OFF + S;
static constexpr long A_OFF  = U_OFF + 256;
static constexpr long B_OFF  = A_OFF + NN;

// ---------------------------------------------------------------------------
// Split-K fp32 GEMM partial: Cp[split] (32 rows x 128 cols per block).
// grid.x = 32 row-blocks, grid.y = K/Kc splits; 256 threads, no LDS.
// Thread (tx=t&31, ty=t>>5): rows ty+8*mr, cols tx+32*mc — 16 independent
// accumulators (ILP) with Kc/4 chain segments of 4 FMAs each.
__global__ __launch_bounds__(256) void gemm_part(
    const float* __restrict__ A, const float* __restrict__ B,
    float* __restrict__ Cp, int K, int Kc) {
  const int t = threadIdx.x;
  const int tx = t & 31;
  const int ty = t >> 5;
  const int row0 = blockIdx.x * 32;
  const int k0 = blockIdx.y * Kc;

  float acc[4][4] = {};

  for (int k = k0; k < k0 + Kc; k += 4) {
    float bv[4][4];
#pragma unroll
    for (int kk = 0; kk < 4; ++kk) {
      const float* Brow = &B[(long)(k + kk) * DD + tx];
#pragma unroll
      for (int mc = 0; mc < 4; ++mc) bv[kk][mc] = Brow[32 * mc];
    }
#pragma unroll
    for (int mr = 0; mr < 4; ++mr) {
      const int r = row0 + ty + 8 * mr;
      const float4 av = *(const float4*)&A[(long)r * K + k];
      const float ar[4] = {av.x, av.y, av.z, av.w};
#pragma unroll
      for (int kk = 0; kk < 4; ++kk)
#pragma unroll
        for (int mc = 0; mc < 4; ++mc) acc[mr][mc] += ar[kk] * bv[kk][mc];
    }
  }

  float* Cs = Cp + (long)blockIdx.y * S;
#pragma unroll
  for (int mr = 0; mr < 4; ++mr) {
    const int r = row0 + ty + 8 * mr;
#pragma unroll
    for (int mc = 0; mc < 4; ++mc)
      Cs[(long)r * DD + tx + 32 * mc] = acc[mr][mc];
  }
}

// ---------------------------------------------------------------------------
// Reduce 16 x-partials -> x ; block 0 also computes u = W2 @ w3[:128].
__global__ __launch_bounds__(256) void reduce_x_u(
    const float* __restrict__ xp, float* __restrict__ x,
    const float* __restrict__ W2, const float* __restrict__ w3,
    float* __restrict__ u) {
  const long i = (long)blockIdx.x * 256 + threadIdx.x;  // 0..131071
  float s = 0.f;
#pragma unroll
  for (int p = 0; p < 16; ++p) s += xp[p * S + i];
  x[i] = s;

  if (blockIdx.x == 0) {
    const int kq = threadIdx.x;  // 0..255
    float uu = 0.f;
#pragma unroll 4
    for (int l = 0; l < DD; ++l) uu += W2[(long)kq * DD + l] * w3[l];
    u[kq] = uu;
  }
}

// ---------------------------------------------------------------------------
// Reduce 32 z-partials -> z ; fused a_i/b_i. grid = 1024 rows, block = 128.
__global__ __launch_bounds__(128) void finalize_z(
    const float* __restrict__ zp, float* __restrict__ z,
    const float* __restrict__ u, float* __restrict__ a, float* __restrict__ b) {
  __shared__ float red[2][2];
  const int i = blockIdx.x;
  const int c = threadIdx.x;  // 0..127 = column
  float s = 0.f;
#pragma unroll
  for (int p = 0; p < 32; ++p) s += zp[p * S + (long)i * DD + c];
  z[(long)i * DD + c] = s;

  const float r = s > 0.f ? s : 0.f;
  float pa = r * u[c];
  float pb = r * u[DD + c];
#pragma unroll
  for (int off = 32; off > 0; off >>= 1) {
    pa += __shfl_down(pa, off);
    pb += __shfl_down(pb, off);
  }
  const int w = c >> 6;
  if ((c & 63) == 0) { red[w][0] = pa; red[w][1] = pb; }
  __syncthreads();
  if (c == 0) {
    a[i] = red[0][0] + red[1][0];
    b[i] = red[0][1] + red[1][1];
  }
}

// ---------------------------------------------------------------------------
// Decode: out[i,j] = sigmoid(a[i] + b[j] + z_i . (z_j * w3[128:])).
// 64x64 tile, 512 threads (8 waves -> 2/SIMD), 2x4 outputs/thread.
// XOR-swizzled LDS: column b128 reads land 2 lanes/bank (free).
__global__ __launch_bounds__(512) void decode_tile(
    const float* __restrict__ z, const float* __restrict__ w3,
    const float* __restrict__ a, const float* __restrict__ b,
    float* __restrict__ out) {
  __shared__ float zl[64 * DD];   // rows i0..
  __shared__ float zwl[64 * DD];  // rows j0.. scaled by w3[128:]
  const int t = threadIdx.x;
  const int i0 = blockIdx.y * 64;
  const int j0 = blockIdx.x * 64;

#pragma unroll
  for (int s = 0; s < 4; ++s) {
    const int q = s * 512 + t;      // 0..2047
    const int r = q >> 5;           // 0..63
    const int k4 = (q & 31) << 2;   // 0..124
    const int sw = r * DD + (k4 ^ ((r & 7) << 2));
    *(float4*)&zl[sw] = *(const float4*)&z[(long)(i0 + r) * DD + k4];
    float4 w = *(const float4*)&z[(long)(j0 + r) * DD + k4];
    const float4 c = *(const float4*)&w3[DD + k4];
    w.x *= c.x; w.y *= c.y; w.z *= c.z; w.w *= c.w;
    *(float4*)&zwl[sw] = w;
  }
  __syncthreads();

  const int tx = t & 15;   // col group
  const int ty = t >> 4;   // 0..31 row
  float acc[2][4] = {};
  for (int k4 = 0; k4 < DD; k4 += 4) {
    float4 ar[2], bc[4];
#pragma unroll
    for (int m = 0; m < 2; ++m) {
      const int R = ty + 32 * m;
      ar[m] = *(const float4*)&zl[R * DD + (k4 ^ ((R & 7) << 2))];
    }
#pragma unroll
    for (int m = 0; m < 4; ++m) {
      const int C = tx + 16 * m;
      bc[m] = *(const float4*)&zwl[C * DD + (k4 ^ ((C & 7) << 2))];
    }
#pragma unroll
    for (int mr = 0; mr < 2; ++mr)
#pragma unroll
      for (int mc = 0; mc < 4; ++mc)
        acc[mr][mc] += ar[mr].x * bc[mc].x + ar[mr].y * bc[mc].y +
                       ar[mr].z * bc[mc].z + ar[mr].w * bc[mc].w;
  }

#pragma unroll
  for (int mr = 0; mr < 2; ++mr) {
    const int i = i0 + ty + 32 * mr;
    const float ai = a[i];
#pragma unroll
    for (int mc = 0; mc < 4; ++mc) {
      const int j = j0 + tx + 16 * mc;
      const float s = ai + b[j] + acc[mr][mc];
      out[(long)i * NN + j] = 1.0f / (1.0f + __expf(-s));
    }
  }
}

// ---------------------------------------------------------------------------
extern "C" void kernel_launch(void* const* d_in, const int* in_sizes, int n_in,
                              void* d_out, int out_size, void* d_ws, size_t ws_size,
                              hipStream_t stream) {
  (void)in_sizes; (void)n_in; (void)out_size; (void)ws_size;
  const float* inputs = (const float*)d_in[0];   // (1024, 512)
  const float* adj    = (const float*)d_in[1];   // (1024, 1024)
  const float* weight = (const float*)d_in[2];   // (512, 128)
  const float* W2     = (const float*)d_in[3];   // (256, 128)
  const float* w3     = (const float*)d_in[4];   // (256,)
  float* out = (float*)d_out;

  float* ws = (float*)d_ws;
  float* xp = ws + XP_OFF;
  float* zp = ws + ZP_OFF;
  float* x  = ws + X_OFF;
  float* z  = ws + Z_OFF;
  float* u  = ws + U_OFF;
  float* a  = ws + A_OFF;
  float* b  = ws + B_OFF;

  // 1) x partials: split-K 16 -> 512 blocks (2/CU)
  gemm_part<<<dim3(32, 16), 256, 0, stream>>>(inputs, weight, xp, DIN, DIN / 16);
  // 2) reduce x (+u)
  reduce_x_u<<<512, 256, 0, stream>>>(xp, x, W2, w3, u);
  // 3) z partials: split-K 32 -> 1024 blocks (4/CU)
  gemm_part<<<dim3(32, 32), 256, 0, stream>>>(adj, x, zp, NN, NN / 32);
  // 4) reduce z + a,b
  finalize_z<<<1024, 128, 0, stream>>>(zp, z, u, a, b);
  // 5) decode
  decode_tile<<<dim3(16, 16), 512, 0, stream>>>(z, w3, a, b, out);
}

// Round 8
// 109.522 us; speedup vs baseline: 1.1581x; 1.0068x over previous
//
#include <hip/hip_runtime.h>
#include <math.h>

#define NN 1024      // N
#define DIN 512      // D_IN
#define DD 128       // D

static constexpr long S = (long)NN * DD;       // 131072 floats per matrix
// ws layout (floats)
static constexpr long XP_OFF = 0;              // 16 x-partials
static constexpr long ZP_OFF = XP_OFF + 16 * S;
static constexpr long X_OFF  = ZP_OFF + 16 * S;  // 16 z-partials
static constexpr long Z_OFF  = X_OFF + S;
static constexpr long U_OFF  = Z_OFF + S;
static constexpr long A_OFF  = U_OFF + 256;
static constexpr long B_OFF  = A_OFF + NN;

// ---------------------------------------------------------------------------
// Split-K fp32 GEMM partial: Cp[split] (32 rows x 128 cols per block).
// grid.x = 32 row-blocks, grid.y = K/Kc splits; 256 threads, no LDS.
// Thread (tx=t&31, ty=t>>5): rows ty+8*mr, cols tx+32*mc — 16 independent
// accumulators (ILP). [R4/R7-verified at 110.1/110.3 µs]
__global__ __launch_bounds__(256) void gemm_part(
    const float* __restrict__ A, const float* __restrict__ B,
    float* __restrict__ Cp, int K, int Kc) {
  const int t = threadIdx.x;
  const int tx = t & 31;
  const int ty = t >> 5;
  const int row0 = blockIdx.x * 32;
  const int k0 = blockIdx.y * Kc;

  float acc[4][4] = {};

  for (int k = k0; k < k0 + Kc; k += 4) {
    float bv[4][4];
#pragma unroll
    for (int kk = 0; kk < 4; ++kk) {
      const float* Brow = &B[(long)(k + kk) * DD + tx];
#pragma unroll
      for (int mc = 0; mc < 4; ++mc) bv[kk][mc] = Brow[32 * mc];
    }
#pragma unroll
    for (int mr = 0; mr < 4; ++mr) {
      const int r = row0 + ty + 8 * mr;
      const float4 av = *(const float4*)&A[(long)r * K + k];
      const float ar[4] = {av.x, av.y, av.z, av.w};
#pragma unroll
      for (int kk = 0; kk < 4; ++kk)
#pragma unroll
        for (int mc = 0; mc < 4; ++mc) acc[mr][mc] += ar[kk] * bv[kk][mc];
    }
  }

  float* Cs = Cp + (long)blockIdx.y * S;
#pragma unroll
  for (int mr = 0; mr < 4; ++mr) {
    const int r = row0 + ty + 8 * mr;
#pragma unroll
    for (int mc = 0; mc < 4; ++mc)
      Cs[(long)r * DD + tx + 32 * mc] = acc[mr][mc];
  }
}

// ---------------------------------------------------------------------------
// Reduce 16 x-partials -> x ; block 0 also computes u = W2 @ w3[:128].
__global__ __launch_bounds__(256) void reduce_x_u(
    const float* __restrict__ xp, float* __restrict__ x,
    const float* __restrict__ W2, const float* __restrict__ w3,
    float* __restrict__ u) {
  const long i = (long)blockIdx.x * 256 + threadIdx.x;  // 0..131071
  float s = 0.f;
#pragma unroll
  for (int p = 0; p < 16; ++p) s += xp[p * S + i];
  x[i] = s;

  if (blockIdx.x == 0) {
    const int kq = threadIdx.x;  // 0..255
    float uu = 0.f;
#pragma unroll 4
    for (int l = 0; l < DD; ++l) uu += W2[(long)kq * DD + l] * w3[l];
    u[kq] = uu;
  }
}

// ---------------------------------------------------------------------------
// Reduce 16 z-partials -> z ; fused a_i/b_i. grid = 1024 rows, block = 128.
__global__ __launch_bounds__(128) void finalize_z(
    const float* __restrict__ zp, float* __restrict__ z,
    const float* __restrict__ u, float* __restrict__ a, float* __restrict__ b) {
  __shared__ float red[2][2];
  const int i = blockIdx.x;
  const int c = threadIdx.x;  // 0..127 = column
  float s = 0.f;
#pragma unroll
  for (int p = 0; p < 16; ++p) s += zp[p * S + (long)i * DD + c];
  z[(long)i * DD + c] = s;

  const float r = s > 0.f ? s : 0.f;
  float pa = r * u[c];
  float pb = r * u[DD + c];
#pragma unroll
  for (int off = 32; off > 0; off >>= 1) {
    pa += __shfl_down(pa, off);
    pb += __shfl_down(pb, off);
  }
  const int w = c >> 6;
  if ((c & 63) == 0) { red[w][0] = pa; red[w][1] = pb; }
  __syncthreads();
  if (c == 0) {
    a[i] = red[0][0] + red[1][0];
    b[i] = red[0][1] + red[1][1];
  }
}

// ---------------------------------------------------------------------------
// Decode (hybrid, R6-verified correct): out[i,j] = sigmoid(a[i]+b[j]+
// z_i.(z_j*w3[128:])). 64x64 tile, 256 threads, 4x4 per thread.
// j-side (scaled) in LDS (32 KB, XOR-swizzled -> conflict-free b128 reads);
// i-side from global z (64-row set = 32 KB, L1-resident; VMEM overlaps LDS).
__global__ __launch_bounds__(256) void k4_decode(
    const float* __restrict__ z, const float* __restrict__ w3,
    const float* __restrict__ a, const float* __restrict__ b,
    float* __restrict__ out) {
  __shared__ float zwl[64 * DD];
  const int t = threadIdx.x;
  const int i0 = blockIdx.y * 64;
  const int j0 = blockIdx.x * 64;

#pragma unroll
  for (int s = 0; s < 8; ++s) {
    const int q = s * 256 + t;
    const int r = q >> 5;
    const int k4 = (q & 31) << 2;
    float4 w = *(const float4*)&z[(long)(j0 + r) * DD + k4];
    const float4 cc = *(const float4*)&w3[DD + k4];
    w.x *= cc.x; w.y *= cc.y; w.z *= cc.z; w.w *= cc.w;
    *(float4*)&zwl[r * DD + (k4 ^ ((r & 7) << 2))] = w;
  }
  __syncthreads();

  const int tx = t & 15;
  const int ty = t >> 4;
  float acc[4][4] = {};
  for (int k4 = 0; k4 < DD; k4 += 4) {
    float4 ar[4], bc[4];
#pragma unroll
    for (int m = 0; m < 4; ++m)  // i-side from global (L1-resident)
      ar[m] = *(const float4*)&z[(long)(i0 + ty + 16 * m) * DD + k4];
#pragma unroll
    for (int m = 0; m < 4; ++m) {
      const int C = tx + 16 * m;
      bc[m] = *(const float4*)&zwl[C * DD + (k4 ^ ((C & 7) << 2))];
    }
#pragma unroll
    for (int mr = 0; mr < 4; ++mr)
#pragma unroll
      for (int mc = 0; mc < 4; ++mc)
        acc[mr][mc] += ar[mr].x * bc[mc].x + ar[mr].y * bc[mc].y +
                       ar[mr].z * bc[mc].z + ar[mr].w * bc[mc].w;
  }

#pragma unroll
  for (int mr = 0; mr < 4; ++mr) {
    const int i = i0 + ty + 16 * mr;
    const float ai = a[i];
#pragma unroll
    for (int mc = 0; mc < 4; ++mc) {
      const int j = j0 + tx + 16 * mc;
      const float sc = ai + b[j] + acc[mr][mc];
      out[(long)i * NN + j] = 1.0f / (1.0f + __expf(-sc));
    }
  }
}

// ---------------------------------------------------------------------------
extern "C" void kernel_launch(void* const* d_in, const int* in_sizes, int n_in,
                              void* d_out, int out_size, void* d_ws, size_t ws_size,
                              hipStream_t stream) {
  (void)in_sizes; (void)n_in; (void)out_size; (void)ws_size;
  const float* inputs = (const float*)d_in[0];   // (1024, 512)
  const float* adj    = (const float*)d_in[1];   // (1024, 1024)
  const float* weight = (const float*)d_in[2];   // (512, 128)
  const float* W2     = (const float*)d_in[3];   // (256, 128)
  const float* w3     = (const float*)d_in[4];   // (256,)
  float* out = (float*)d_out;

  float* ws = (float*)d_ws;
  float* xp = ws + XP_OFF;
  float* zp = ws + ZP_OFF;
  float* x  = ws + X_OFF;
  float* z  = ws + Z_OFF;
  float* u  = ws + U_OFF;
  float* a  = ws + A_OFF;
  float* b  = ws + B_OFF;

  // 1) x partials: split-K 16 -> 512 blocks (2/CU)
  gemm_part<<<dim3(32, 16), 256, 0, stream>>>(inputs, weight, xp, DIN, DIN / 16);
  // 2) reduce x (+u)
  reduce_x_u<<<512, 256, 0, stream>>>(xp, x, W2, w3, u);
  // 3) z partials: split-K 16 -> 512 blocks (Kc=64, 8 waves/CU)
  gemm_part<<<dim3(32, 16), 256, 0, stream>>>(adj, x, zp, NN, NN / 16);
  // 4) reduce z + a,b
  finalize_z<<<1024, 128, 0, stream>>>(zp, z, u, a, b);
  // 5) decode (hybrid LDS/L1)
  k4_decode<<<dim3(16, 16), 256, 0, stream>>>(z, w3, a, b, out);
}